// Round 1
// baseline (1001.986 us; speedup 1.0000x reference)
//
#include <hip/hip_runtime.h>
#include <math.h>

// Problem constants (B=4, m=4096, C=256, H=W=384)
#define Mm 4096
#define Cc 256
#define Hh 384
#define Ww 384
#define HW (Hh * Ww)

// ---------------------------------------------------------------------------
// K3: one block per (b,c) plane (blockIdx.x = L = 4*c + b, L in [0,1024)).
//  Phase A: coalesced float4 scan of the plane -> per-plane mean & max.
//  Phase B: scrambled gather -> pool column + center column, written
//           column-major to workspace (coalesced).
// Mapping derived from the reference's reshape chain:
//   out batch b2 = L>>8, out channel c2 = L&255 ; this plane produces the
//   entire output column (b2, :, c2).
//   For output row i' and tap k': j' = (k'<<12)+i', kpt i = j'/9, offset
//   k = j'%9, pixel = clip(x_i + k/3-1) * W + clip(y_i + k%3-1).
// ---------------------------------------------------------------------------
__global__ __launch_bounds__(256) void k3_scan_gather(
    const float* __restrict__ kpts, const float* __restrict__ seg,
    const float* __restrict__ conv_w, const float* __restrict__ conv_b,
    float* __restrict__ pool_ws, float* __restrict__ cent_ws,
    float* __restrict__ avg_ws, float* __restrict__ max_ws)
{
    const int p = blockIdx.x;        // L in [0,1024)
    const int b  = p & 3;            // segment batch
    const int cc = p >> 2;           // segment channel
    const int t  = threadIdx.x;

    const float* plane = seg + (size_t)(b * Cc + cc) * HW;

    __shared__ short2 sxy[Mm];       // 16 KB: keypoint integer coords, batch b
    __shared__ float red[16];

    // stage keypoint coords for batch b (coalesced)
    const float* kb = kpts + (size_t)b * Mm * 2;
    for (int i = t; i < Mm; i += 256) {
        float kx = kb[2 * i];
        float ky = kb[2 * i + 1];
        short xi = (short)floorf(kx * (float)Hh);
        short yi = (short)floorf(ky * (float)Ww);
        sxy[i] = make_short2(xi, yi);
    }

    // Phase A: plane scan, sum & max (vectorized; HW/4 = 36864 = 144*256)
    const float4* plane4 = (const float4*)plane;
    float lsum = 0.0f, lmax = -INFINITY;
    for (int idx = t; idx < HW / 4; idx += 256) {
        float4 v = plane4[idx];
        lsum += (v.x + v.y) + (v.z + v.w);
        lmax = fmaxf(lmax, fmaxf(fmaxf(v.x, v.y), fmaxf(v.z, v.w)));
    }
    #pragma unroll
    for (int off = 32; off > 0; off >>= 1) {
        lsum += __shfl_down(lsum, off);
        lmax = fmaxf(lmax, __shfl_down(lmax, off));
    }
    const int wave = t >> 6;
    if ((t & 63) == 0) { red[wave] = lsum; red[8 + wave] = lmax; }
    __syncthreads();                 // also fences sxy for phase B
    if (t == 0) {
        float s  = ((red[0] + red[1]) + (red[2] + red[3]));
        float mx = fmaxf(fmaxf(red[8], red[9]), fmaxf(red[10], red[11]));
        avg_ws[b * Cc + cc] = s * (1.0f / (float)HW);
        max_ws[b * Cc + cc] = mx;
    }

    // Phase B: gather
    float cw[9];
    #pragma unroll
    for (int k = 0; k < 9; ++k) cw[k] = conv_w[k];
    const float cb = conv_b[0];

    float* pool_col = pool_ws + (size_t)p * Mm;
    float* cent_col = cent_ws + (size_t)p * Mm;

    for (int ip = t; ip < Mm; ip += 256) {
        float pool = cb;
        float center = 0.0f;
        #pragma unroll
        for (int kp = 0; kp < 9; ++kp) {
            int j = (kp << 12) + ip;        // j' in [0, 36864)
            int i = j / 9;                  // keypoint index (magic-mul)
            int k = j - i * 9;              // neighbor offset index
            short2 xy = sxy[i];
            int dx = (k / 3) - 1;
            int dy = (k - (k / 3) * 3) - 1;
            int xo = xy.x + dx;
            int yo = xy.y + dy;
            xo = min(max(xo, 0), Hh - 1);
            yo = min(max(yo, 0), Ww - 1);
            float v = plane[xo * Ww + yo];
            pool = fmaf(cw[kp], v, pool);
            if (kp == 4) center = v;
        }
        pool_col[ip] = pool;                // coalesced column writes
        cent_col[ip] = center;
    }
}

// ---------------------------------------------------------------------------
// K2: CBAM channel-attention MLP. One block per output batch b'.
//   s[b,c] = sigmoid( relu(avg@W1^T)@W2^T + relu(max@W1^T)@W2^T )[c]
// ---------------------------------------------------------------------------
__global__ __launch_bounds__(256) void k2_mlp(
    const float* __restrict__ avg_ws, const float* __restrict__ max_ws,
    const float* __restrict__ w1, const float* __restrict__ w2,
    float* __restrict__ s_ws)
{
    const int bb = blockIdx.x;
    const int t  = threadIdx.x;
    __shared__ float va[Cc], vm[Cc], g[Cc];
    va[t] = avg_ws[bb * Cc + t];
    vm[t] = max_ws[bb * Cc + t];
    __syncthreads();
    float ha = 0.0f, hm = 0.0f;
    const float* w1r = w1 + (size_t)t * Cc;   // W1 row t
    for (int c = 0; c < Cc; ++c) {
        float w = w1r[c];
        ha = fmaf(w, va[c], ha);
        hm = fmaf(w, vm[c], hm);
    }
    g[t] = fmaxf(ha, 0.0f) + fmaxf(hm, 0.0f);
    __syncthreads();
    float o = 0.0f;
    const float* w2r = w2 + (size_t)t * Cc;   // W2 row t
    for (int c = 0; c < Cc; ++c) o = fmaf(w2r[c], g[c], o);
    s_ws[bb * Cc + t] = 1.0f / (1.0f + expf(-o));
}

// ---------------------------------------------------------------------------
// K4: LDS-transpose + confidence + combine.
//  grid = (Mm/16, 4). Block handles a 16(i') x 256(c') tile of batch b'.
//  Reads pool/center column-major (coalesced), computes
//  conf[i'] = center(i',:)·lin_w + lin_b, writes
//  out = (1-conf)*pool + center + s  row-major (coalesced).
// ---------------------------------------------------------------------------
__global__ __launch_bounds__(256) void k4_final(
    const float* __restrict__ pool_ws, const float* __restrict__ cent_ws,
    const float* __restrict__ lin_w, const float* __restrict__ lin_b,
    const float* __restrict__ s_ws, float* __restrict__ out)
{
    const int bb = blockIdx.y;
    const int i0 = blockIdx.x * 16;
    const int t  = threadIdx.x;
    __shared__ float tp[Cc][17];   // +1 pad: kill 16-stride bank conflicts
    __shared__ float tc[Cc][17];
    __shared__ float conf[16];

    const int r  = t & 15;   // i' offset within tile (load phase)
    const int cg = t >> 4;   // c' group (load phase)

    for (int pass = 0; pass < 16; ++pass) {
        int cp = pass * 16 + cg;
        size_t gidx = (size_t)(bb * Cc + cp) * Mm + i0 + r;  // coalesced per 16-lane group
        tp[cp][r] = pool_ws[gidx];
        tc[cp][r] = cent_ws[gidx];
    }
    if (t < 16) conf[t] = 0.0f;
    __syncthreads();

    float part = 0.0f;
    #pragma unroll
    for (int it = 0; it < 16; ++it) {
        int cp = it * 16 + cg;
        part = fmaf(tc[cp][r], lin_w[cp], part);
    }
    atomicAdd(&conf[r], part);
    __syncthreads();

    const float lb = lin_b[0];
    for (int pass = 0; pass < 16; ++pass) {
        int rr = t >> 4;                // i' offset (store phase)
        int cp = pass * 16 + (t & 15);  // c' (store phase) -> coalesced
        float cf = conf[rr] + lb;
        float val = (1.0f - cf) * tp[cp][rr] + tc[cp][rr] + s_ws[bb * Cc + cp];
        out[(size_t)(bb * Mm + i0 + rr) * Cc + cp] = val;
    }
}

// ---------------------------------------------------------------------------
// Workspace layout (floats):
//   [0)                pool_ws  1024*4096
//   [1024*4096)        cent_ws  1024*4096
//   [2*1024*4096)      avg_ws   1024
//   +1024              max_ws   1024
//   +2048              s_ws     1024
// Total = 33,562,624 bytes.
// ---------------------------------------------------------------------------
extern "C" void kernel_launch(void* const* d_in, const int* in_sizes, int n_in,
                              void* d_out, int out_size, void* d_ws, size_t ws_size,
                              hipStream_t stream) {
    const float* kpts   = (const float*)d_in[0];
    const float* seg    = (const float*)d_in[1];
    const float* conv_w = (const float*)d_in[2];
    const float* conv_b = (const float*)d_in[3];
    const float* lin_w  = (const float*)d_in[4];
    const float* lin_b  = (const float*)d_in[5];
    const float* w1     = (const float*)d_in[6];
    const float* w2     = (const float*)d_in[7];
    float* out = (float*)d_out;

    float* ws      = (float*)d_ws;
    float* pool_ws = ws;
    float* cent_ws = ws + (size_t)1024 * Mm;
    float* avg_ws  = ws + (size_t)2 * 1024 * Mm;
    float* max_ws  = avg_ws + 1024;
    float* s_ws    = avg_ws + 2048;

    hipLaunchKernelGGL(k3_scan_gather, dim3(1024), dim3(256), 0, stream,
                       kpts, seg, conv_w, conv_b, pool_ws, cent_ws, avg_ws, max_ws);
    hipLaunchKernelGGL(k2_mlp, dim3(4), dim3(256), 0, stream,
                       avg_ws, max_ws, w1, w2, s_ws);
    hipLaunchKernelGGL(k4_final, dim3(Mm / 16, 4), dim3(256), 0, stream,
                       pool_ws, cent_ws, lin_w, lin_b, s_ws, out);
}

// Round 2
// 915.285 us; speedup vs baseline: 1.0947x; 1.0947x over previous
//
#include <hip/hip_runtime.h>
#include <math.h>

// Problem constants (B=4, m=4096, C=256, H=W=384)
#define Mm 4096
#define Cc 256
#define Hh 384
#define Ww 384
#define HW (Hh * Ww)
#define NTAP (Mm * 9)   // 36864 taps per batch == V size per plane

// ---------------------------------------------------------------------------
// K_P: per-batch tap bucketing by clipped row.
// For each keypoint i and tap k (dx=k/3-1, dy=k%3-1):
//   xo = clip(x_i+dx), yo = clip(y_i+dy); bucket key = xo.
// Stores pixel offset (xo*W+yo) and V index (i*9+k), bucket-sorted by row,
// plus row_start[385] prefix offsets. Identity: V[i*9+k] == V[j'] where
// j' = k'*4096 + i2 is the output-space tap index -> epilogue is trivial.
// ---------------------------------------------------------------------------
__global__ __launch_bounds__(384) void k_buckets(
    const float* __restrict__ kpts,
    unsigned int* __restrict__ pix_ws,      // [4][NTAP]
    unsigned short* __restrict__ vidx_ws,   // [4][NTAP]
    int* __restrict__ row_start_ws)         // [4][385]
{
    const int b = blockIdx.x;
    const int t = threadIdx.x;              // 0..383
    __shared__ int cnt[Hh];
    __shared__ int offs[Hh + 1];
    __shared__ int cur[Hh];

    cnt[t] = 0;
    __syncthreads();

    const float* kb = kpts + (size_t)b * Mm * 2;
    for (int i = t; i < Mm; i += 384) {
        int xi = (int)floorf(kb[2 * i] * (float)Hh);
        #pragma unroll
        for (int dx = -1; dx <= 1; ++dx) {
            int xo = min(max(xi + dx, 0), Hh - 1);
            atomicAdd(&cnt[xo], 3);         // 3 dy-taps share this row
        }
    }
    __syncthreads();

    // Hillis-Steele inclusive scan over 384 entries (block == 384 threads)
    for (int d = 1; d < Hh; d <<= 1) {
        int add = (t >= d) ? cnt[t - d] : 0;
        __syncthreads();
        cnt[t] += add;
        __syncthreads();
    }
    offs[t + 1] = cnt[t];
    if (t == 0) offs[0] = 0;
    __syncthreads();
    cur[t] = offs[t];
    row_start_ws[b * 385 + t] = offs[t];
    if (t == 383) row_start_ws[b * 385 + 384] = offs[384];
    __syncthreads();

    for (int i = t; i < Mm; i += 384) {
        int xi = (int)floorf(kb[2 * i] * (float)Hh);
        int yi = (int)floorf(kb[2 * i + 1] * (float)Ww);
        #pragma unroll
        for (int k = 0; k < 9; ++k) {
            int xo = min(max(xi + (k / 3) - 1, 0), Hh - 1);
            int yo = min(max(yi + (k % 3) - 1, 0), Ww - 1);
            int pos = atomicAdd(&cur[xo], 1);
            pix_ws[(size_t)b * NTAP + pos] = (unsigned int)(xo * Ww + yo);
            vidx_ws[(size_t)b * NTAP + pos] = (unsigned short)(i * 9 + k);
        }
    }
}

// ---------------------------------------------------------------------------
// K3': one block per (b,c) plane (p = blockIdx.x; b=p&3, c=p>>2; serves
// output column b2=p>>8, c2=p&255 — same mapping as R1, verified PASS).
//  - Stream plane in 32-row chunks (float4 x12/thread): sum & max.
//  - Immediately gather that chunk's bucketed taps from global (L2-hot)
//    into V[36864] in LDS (144 KB).
//  - Epilogue: pool(i2)=cb+sum_k w[k]*V[k*4096+i2], cent=V[4*4096+i2];
//    conflict-free LDS reads, coalesced column writes.
// ---------------------------------------------------------------------------
__global__ __launch_bounds__(256) void k3_gather(
    const float* __restrict__ seg,
    const float* __restrict__ conv_w, const float* __restrict__ conv_b,
    const unsigned int* __restrict__ pix_ws,
    const unsigned short* __restrict__ vidx_ws,
    const int* __restrict__ row_start_ws,
    float* __restrict__ pool_ws, float* __restrict__ cent_ws,
    float* __restrict__ avg_ws, float* __restrict__ max_ws)
{
    __shared__ float V[NTAP];    // 144 KB
    __shared__ float red[16];

    const int p = blockIdx.x;
    const int b = p & 3;
    const int cc = p >> 2;
    const int t = threadIdx.x;

    const float* plane = seg + (size_t)(b * Cc + cc) * HW;
    const unsigned int* pix = pix_ws + (size_t)b * NTAP;
    const unsigned short* vix = vidx_ws + (size_t)b * NTAP;
    const int* rs = row_start_ws + b * 385;

    float lsum = 0.0f, lmax = -INFINITY;

    // 12 chunks of 32 rows; 32*384/4 = 3072 float4 per chunk = 12/thread
    for (int ch = 0; ch < 12; ++ch) {
        const float4* base = (const float4*)(plane + (size_t)ch * 32 * Ww);
        float4 v[12];
        #pragma unroll
        for (int u = 0; u < 12; ++u) v[u] = base[t + 256 * u];
        #pragma unroll
        for (int u = 0; u < 12; ++u) {
            lsum += (v[u].x + v[u].y) + (v[u].z + v[u].w);
            lmax = fmaxf(lmax, fmaxf(fmaxf(v[u].x, v[u].y), fmaxf(v[u].z, v[u].w)));
        }
        // gather this chunk's taps (rows ch*32 .. ch*32+31) — L2-warm
        int e0 = rs[ch * 32];
        int e1 = rs[ch * 32 + 32];
        for (int e = e0 + t; e < e1; e += 256) {
            V[vix[e]] = plane[pix[e]];
        }
    }

    // block reduce sum/max
    #pragma unroll
    for (int off = 32; off > 0; off >>= 1) {
        lsum += __shfl_down(lsum, off);
        lmax = fmaxf(lmax, __shfl_down(lmax, off));
    }
    const int wave = t >> 6;
    if ((t & 63) == 0) { red[wave] = lsum; red[8 + wave] = lmax; }
    __syncthreads();   // fences red AND all V writes
    if (t == 0) {
        float s  = ((red[0] + red[1]) + (red[2] + red[3]));
        float mx = fmaxf(fmaxf(red[8], red[9]), fmaxf(red[10], red[11]));
        avg_ws[b * Cc + cc] = s * (1.0f / (float)HW);
        max_ws[b * Cc + cc] = mx;
    }

    // epilogue
    float cw[9];
    #pragma unroll
    for (int k = 0; k < 9; ++k) cw[k] = conv_w[k];
    const float cb = conv_b[0];

    float* pool_col = pool_ws + (size_t)p * Mm;
    float* cent_col = cent_ws + (size_t)p * Mm;
    for (int i2 = t; i2 < Mm; i2 += 256) {
        float pool = cb;
        #pragma unroll
        for (int kp = 0; kp < 9; ++kp)
            pool = fmaf(cw[kp], V[kp * Mm + i2], pool);
        pool_col[i2] = pool;           // coalesced
        cent_col[i2] = V[4 * Mm + i2];
    }
}

// ---------------------------------------------------------------------------
// K2: CBAM channel-attention MLP (unchanged from R1).
// ---------------------------------------------------------------------------
__global__ __launch_bounds__(256) void k2_mlp(
    const float* __restrict__ avg_ws, const float* __restrict__ max_ws,
    const float* __restrict__ w1, const float* __restrict__ w2,
    float* __restrict__ s_ws)
{
    const int bb = blockIdx.x;
    const int t  = threadIdx.x;
    __shared__ float va[Cc], vm[Cc], g[Cc];
    va[t] = avg_ws[bb * Cc + t];
    vm[t] = max_ws[bb * Cc + t];
    __syncthreads();
    float ha = 0.0f, hm = 0.0f;
    const float* w1r = w1 + (size_t)t * Cc;
    for (int c = 0; c < Cc; ++c) {
        float w = w1r[c];
        ha = fmaf(w, va[c], ha);
        hm = fmaf(w, vm[c], hm);
    }
    g[t] = fmaxf(ha, 0.0f) + fmaxf(hm, 0.0f);
    __syncthreads();
    float o = 0.0f;
    const float* w2r = w2 + (size_t)t * Cc;
    for (int c = 0; c < Cc; ++c) o = fmaf(w2r[c], g[c], o);
    s_ws[bb * Cc + t] = 1.0f / (1.0f + expf(-o));
}

// ---------------------------------------------------------------------------
// K4: LDS-transpose + confidence + combine (unchanged from R1, PASS).
// ---------------------------------------------------------------------------
__global__ __launch_bounds__(256) void k4_final(
    const float* __restrict__ pool_ws, const float* __restrict__ cent_ws,
    const float* __restrict__ lin_w, const float* __restrict__ lin_b,
    const float* __restrict__ s_ws, float* __restrict__ out)
{
    const int bb = blockIdx.y;
    const int i0 = blockIdx.x * 16;
    const int t  = threadIdx.x;
    __shared__ float tp[Cc][17];
    __shared__ float tc[Cc][17];
    __shared__ float conf[16];

    const int r  = t & 15;
    const int cg = t >> 4;

    for (int pass = 0; pass < 16; ++pass) {
        int cp = pass * 16 + cg;
        size_t gidx = (size_t)(bb * Cc + cp) * Mm + i0 + r;
        tp[cp][r] = pool_ws[gidx];
        tc[cp][r] = cent_ws[gidx];
    }
    if (t < 16) conf[t] = 0.0f;
    __syncthreads();

    float part = 0.0f;
    #pragma unroll
    for (int it = 0; it < 16; ++it) {
        int cp = it * 16 + cg;
        part = fmaf(tc[cp][r], lin_w[cp], part);
    }
    atomicAdd(&conf[r], part);
    __syncthreads();

    const float lb = lin_b[0];
    for (int pass = 0; pass < 16; ++pass) {
        int rr = t >> 4;
        int cp = pass * 16 + (t & 15);
        float cf = conf[rr] + lb;
        float val = (1.0f - cf) * tp[cp][rr] + tc[cp][rr] + s_ws[bb * Cc + cp];
        out[(size_t)(bb * Mm + i0 + rr) * Cc + cp] = val;
    }
}

// ---------------------------------------------------------------------------
// Workspace layout (bytes, float unless noted):
//   pool_ws   1024*4096 f            @ 0
//   cent_ws   1024*4096 f            @ 16 MB
//   avg_ws    1024 f | max_ws 1024 f | s_ws 1024 f
//   pix_ws    4*36864 u32
//   vidx_ws   4*36864 u16
//   row_start 4*385 i32
// Total ~= 34.5 MB.
// ---------------------------------------------------------------------------
extern "C" void kernel_launch(void* const* d_in, const int* in_sizes, int n_in,
                              void* d_out, int out_size, void* d_ws, size_t ws_size,
                              hipStream_t stream) {
    const float* kpts   = (const float*)d_in[0];
    const float* seg    = (const float*)d_in[1];
    const float* conv_w = (const float*)d_in[2];
    const float* conv_b = (const float*)d_in[3];
    const float* lin_w  = (const float*)d_in[4];
    const float* lin_b  = (const float*)d_in[5];
    const float* w1     = (const float*)d_in[6];
    const float* w2     = (const float*)d_in[7];
    float* out = (float*)d_out;

    char* ws = (char*)d_ws;
    float* pool_ws = (float*)ws;                                   ws += (size_t)1024 * Mm * 4;
    float* cent_ws = (float*)ws;                                   ws += (size_t)1024 * Mm * 4;
    float* avg_ws  = (float*)ws;                                   ws += 1024 * 4;
    float* max_ws  = (float*)ws;                                   ws += 1024 * 4;
    float* s_ws    = (float*)ws;                                   ws += 1024 * 4;
    unsigned int*   pix_ws  = (unsigned int*)ws;                   ws += (size_t)4 * NTAP * 4;
    unsigned short* vidx_ws = (unsigned short*)ws;                 ws += (size_t)4 * NTAP * 2;
    int* row_start_ws = (int*)ws;

    hipLaunchKernelGGL(k_buckets, dim3(4), dim3(384), 0, stream,
                       kpts, pix_ws, vidx_ws, row_start_ws);
    hipLaunchKernelGGL(k3_gather, dim3(1024), dim3(256), 0, stream,
                       seg, conv_w, conv_b, pix_ws, vidx_ws, row_start_ws,
                       pool_ws, cent_ws, avg_ws, max_ws);
    hipLaunchKernelGGL(k2_mlp, dim3(4), dim3(256), 0, stream,
                       avg_ws, max_ws, w1, w2, s_ws);
    hipLaunchKernelGGL(k4_final, dim3(Mm / 16, 4), dim3(256), 0, stream,
                       pool_ws, cent_ws, lin_w, lin_b, s_ws, out);
}

// Round 3
// 872.788 us; speedup vs baseline: 1.1480x; 1.0487x over previous
//
#include <hip/hip_runtime.h>
#include <math.h>

// Problem constants (B=4, m=4096, C=256, H=W=384)
#define Mm 4096
#define Cc 256
#define Hh 384
#define Ww 384
#define HW (Hh * Ww)
#define NTAP (Mm * 9)   // 36864 taps per batch == V size per plane

// ---------------------------------------------------------------------------
// K_P: per-batch tap bucketing by clipped row (1024 threads now).
// For each keypoint i and tap k (dx=k/3-1, dy=k%3-1):
//   xo = clip(x_i+dx), yo = clip(y_i+dy); bucket key = xo.
// Stores pixel offset (xo*W+yo) and V index (i*9+k), bucket-sorted by row,
// plus row_start[385] prefix offsets. Identity: V[i*9+k] == V[j'] where
// j' = k'*4096 + i2 is the output-space tap index -> epilogue is trivial.
// ---------------------------------------------------------------------------
__global__ __launch_bounds__(1024) void k_buckets(
    const float* __restrict__ kpts,
    unsigned int* __restrict__ pix_ws,      // [4][NTAP]
    unsigned short* __restrict__ vidx_ws,   // [4][NTAP]
    int* __restrict__ row_start_ws)         // [4][385]
{
    const int b = blockIdx.x;
    const int t = threadIdx.x;              // 0..1023
    __shared__ int cnt[Hh];
    __shared__ int offs[Hh + 1];
    __shared__ int cur[Hh];

    if (t < Hh) cnt[t] = 0;
    __syncthreads();

    const float* kb = kpts + (size_t)b * Mm * 2;
    for (int i = t; i < Mm; i += 1024) {
        int xi = (int)floorf(kb[2 * i] * (float)Hh);
        #pragma unroll
        for (int dx = -1; dx <= 1; ++dx) {
            int xo = min(max(xi + dx, 0), Hh - 1);
            atomicAdd(&cnt[xo], 3);         // 3 dy-taps share this row
        }
    }
    __syncthreads();

    // Hillis-Steele inclusive scan over 384 entries (all threads hit barriers)
    for (int d = 1; d < Hh; d <<= 1) {
        int add = 0;
        if (t < Hh && t >= d) add = cnt[t - d];
        __syncthreads();
        if (t < Hh) cnt[t] += add;
        __syncthreads();
    }
    if (t < Hh) {
        offs[t + 1] = cnt[t];
        if (t == 0) offs[0] = 0;
    }
    __syncthreads();
    if (t < Hh) {
        cur[t] = offs[t];
        row_start_ws[b * 385 + t] = offs[t];
        if (t == Hh - 1) row_start_ws[b * 385 + Hh] = offs[Hh];
    }
    __syncthreads();

    for (int i = t; i < Mm; i += 1024) {
        int xi = (int)floorf(kb[2 * i] * (float)Hh);
        int yi = (int)floorf(kb[2 * i + 1] * (float)Ww);
        #pragma unroll
        for (int k = 0; k < 9; ++k) {
            int xo = min(max(xi + (k / 3) - 1, 0), Hh - 1);
            int yo = min(max(yi + (k % 3) - 1, 0), Ww - 1);
            int pos = atomicAdd(&cur[xo], 1);
            pix_ws[(size_t)b * NTAP + pos] = (unsigned int)(xo * Ww + yo);
            vidx_ws[(size_t)b * NTAP + pos] = (unsigned short)(i * 9 + k);
        }
    }
}

// ---------------------------------------------------------------------------
// K3': one block per (b,c) plane (p = blockIdx.x; b=p&3, c=p>>2; serves
// output column b2=p>>8, c2=p&255).  NOW 1024 THREADS (16 waves/CU):
// 144 KB LDS already pins 1 block/CU, so the bigger block is free occupancy.
//  - Stream plane in 32-row chunks (3x float4/thread): sum & max.
//  - Gather that chunk's bucketed taps from global (L2-hot) into V[36864].
//  - Epilogue: pool/cent columns, conflict-free LDS, coalesced writes.
// ---------------------------------------------------------------------------
__global__ __launch_bounds__(1024) void k3_gather(
    const float* __restrict__ seg,
    const float* __restrict__ conv_w, const float* __restrict__ conv_b,
    const unsigned int* __restrict__ pix_ws,
    const unsigned short* __restrict__ vidx_ws,
    const int* __restrict__ row_start_ws,
    float* __restrict__ pool_ws, float* __restrict__ cent_ws,
    float* __restrict__ avg_ws, float* __restrict__ max_ws)
{
    __shared__ float V[NTAP];    // 144 KB
    __shared__ float red[32];    // 16 wave sums + 16 wave maxes

    const int p = blockIdx.x;
    const int b = p & 3;
    const int cc = p >> 2;
    const int t = threadIdx.x;

    const float* plane = seg + (size_t)(b * Cc + cc) * HW;
    const unsigned int* pix = pix_ws + (size_t)b * NTAP;
    const unsigned short* vix = vidx_ws + (size_t)b * NTAP;
    const int* rs = row_start_ws + b * 385;

    float lsum = 0.0f, lmax = -INFINITY;

    // 12 chunks of 32 rows; 32*384/4 = 3072 float4 per chunk = 3/thread
    for (int ch = 0; ch < 12; ++ch) {
        const float4* base = (const float4*)(plane + (size_t)ch * 32 * Ww);
        float4 v0 = base[t];
        float4 v1 = base[t + 1024];
        float4 v2 = base[t + 2048];
        lsum += (v0.x + v0.y) + (v0.z + v0.w);
        lmax = fmaxf(lmax, fmaxf(fmaxf(v0.x, v0.y), fmaxf(v0.z, v0.w)));
        lsum += (v1.x + v1.y) + (v1.z + v1.w);
        lmax = fmaxf(lmax, fmaxf(fmaxf(v1.x, v1.y), fmaxf(v1.z, v1.w)));
        lsum += (v2.x + v2.y) + (v2.z + v2.w);
        lmax = fmaxf(lmax, fmaxf(fmaxf(v2.x, v2.y), fmaxf(v2.z, v2.w)));
        // gather this chunk's taps (rows ch*32 .. ch*32+31) — L2-warm
        int e0 = rs[ch * 32];
        int e1 = rs[ch * 32 + 32];
        for (int e = e0 + t; e < e1; e += 1024) {
            V[vix[e]] = plane[pix[e]];
        }
    }

    // block reduce sum/max (16 waves)
    #pragma unroll
    for (int off = 32; off > 0; off >>= 1) {
        lsum += __shfl_down(lsum, off);
        lmax = fmaxf(lmax, __shfl_down(lmax, off));
    }
    const int wave = t >> 6;
    if ((t & 63) == 0) { red[wave] = lsum; red[16 + wave] = lmax; }
    __syncthreads();   // fences red AND all V writes
    if (t == 0) {
        float s = 0.0f, mx = -INFINITY;
        #pragma unroll
        for (int w = 0; w < 16; ++w) {
            s += red[w];
            mx = fmaxf(mx, red[16 + w]);
        }
        avg_ws[b * Cc + cc] = s * (1.0f / (float)HW);
        max_ws[b * Cc + cc] = mx;
    }

    // epilogue
    float cw[9];
    #pragma unroll
    for (int k = 0; k < 9; ++k) cw[k] = conv_w[k];
    const float cb = conv_b[0];

    float* pool_col = pool_ws + (size_t)p * Mm;
    float* cent_col = cent_ws + (size_t)p * Mm;
    #pragma unroll
    for (int i2 = t; i2 < Mm; i2 += 1024) {
        float pool = cb;
        #pragma unroll
        for (int kp = 0; kp < 9; ++kp)
            pool = fmaf(cw[kp], V[kp * Mm + i2], pool);
        pool_col[i2] = pool;           // coalesced
        cent_col[i2] = V[4 * Mm + i2];
    }
}

// ---------------------------------------------------------------------------
// K2: CBAM channel-attention MLP (unchanged, PASS).
// ---------------------------------------------------------------------------
__global__ __launch_bounds__(256) void k2_mlp(
    const float* __restrict__ avg_ws, const float* __restrict__ max_ws,
    const float* __restrict__ w1, const float* __restrict__ w2,
    float* __restrict__ s_ws)
{
    const int bb = blockIdx.x;
    const int t  = threadIdx.x;
    __shared__ float va[Cc], vm[Cc], g[Cc];
    va[t] = avg_ws[bb * Cc + t];
    vm[t] = max_ws[bb * Cc + t];
    __syncthreads();
    float ha = 0.0f, hm = 0.0f;
    const float* w1r = w1 + (size_t)t * Cc;
    for (int c = 0; c < Cc; ++c) {
        float w = w1r[c];
        ha = fmaf(w, va[c], ha);
        hm = fmaf(w, vm[c], hm);
    }
    g[t] = fmaxf(ha, 0.0f) + fmaxf(hm, 0.0f);
    __syncthreads();
    float o = 0.0f;
    const float* w2r = w2 + (size_t)t * Cc;
    for (int c = 0; c < Cc; ++c) o = fmaf(w2r[c], g[c], o);
    s_ws[bb * Cc + t] = 1.0f / (1.0f + expf(-o));
}

// ---------------------------------------------------------------------------
// K4: LDS-transpose + confidence + combine (unchanged, PASS).
// ---------------------------------------------------------------------------
__global__ __launch_bounds__(256) void k4_final(
    const float* __restrict__ pool_ws, const float* __restrict__ cent_ws,
    const float* __restrict__ lin_w, const float* __restrict__ lin_b,
    const float* __restrict__ s_ws, float* __restrict__ out)
{
    const int bb = blockIdx.y;
    const int i0 = blockIdx.x * 16;
    const int t  = threadIdx.x;
    __shared__ float tp[Cc][17];
    __shared__ float tc[Cc][17];
    __shared__ float conf[16];

    const int r  = t & 15;
    const int cg = t >> 4;

    for (int pass = 0; pass < 16; ++pass) {
        int cp = pass * 16 + cg;
        size_t gidx = (size_t)(bb * Cc + cp) * Mm + i0 + r;
        tp[cp][r] = pool_ws[gidx];
        tc[cp][r] = cent_ws[gidx];
    }
    if (t < 16) conf[t] = 0.0f;
    __syncthreads();

    float part = 0.0f;
    #pragma unroll
    for (int it = 0; it < 16; ++it) {
        int cp = it * 16 + cg;
        part = fmaf(tc[cp][r], lin_w[cp], part);
    }
    atomicAdd(&conf[r], part);
    __syncthreads();

    const float lb = lin_b[0];
    for (int pass = 0; pass < 16; ++pass) {
        int rr = t >> 4;
        int cp = pass * 16 + (t & 15);
        float cf = conf[rr] + lb;
        float val = (1.0f - cf) * tp[cp][rr] + tc[cp][rr] + s_ws[bb * Cc + cp];
        out[(size_t)(bb * Mm + i0 + rr) * Cc + cp] = val;
    }
}

// ---------------------------------------------------------------------------
// Workspace layout (bytes):
//   pool_ws   1024*4096 f
//   cent_ws   1024*4096 f
//   avg_ws 1024 f | max_ws 1024 f | s_ws 1024 f
//   pix_ws    4*36864 u32
//   vidx_ws   4*36864 u16
//   row_start 4*385 i32
// Total ~= 34.5 MB.
// ---------------------------------------------------------------------------
extern "C" void kernel_launch(void* const* d_in, const int* in_sizes, int n_in,
                              void* d_out, int out_size, void* d_ws, size_t ws_size,
                              hipStream_t stream) {
    const float* kpts   = (const float*)d_in[0];
    const float* seg    = (const float*)d_in[1];
    const float* conv_w = (const float*)d_in[2];
    const float* conv_b = (const float*)d_in[3];
    const float* lin_w  = (const float*)d_in[4];
    const float* lin_b  = (const float*)d_in[5];
    const float* w1     = (const float*)d_in[6];
    const float* w2     = (const float*)d_in[7];
    float* out = (float*)d_out;

    char* ws = (char*)d_ws;
    float* pool_ws = (float*)ws;                                   ws += (size_t)1024 * Mm * 4;
    float* cent_ws = (float*)ws;                                   ws += (size_t)1024 * Mm * 4;
    float* avg_ws  = (float*)ws;                                   ws += 1024 * 4;
    float* max_ws  = (float*)ws;                                   ws += 1024 * 4;
    float* s_ws    = (float*)ws;                                   ws += 1024 * 4;
    unsigned int*   pix_ws  = (unsigned int*)ws;                   ws += (size_t)4 * NTAP * 4;
    unsigned short* vidx_ws = (unsigned short*)ws;                 ws += (size_t)4 * NTAP * 2;
    int* row_start_ws = (int*)ws;

    hipLaunchKernelGGL(k_buckets, dim3(4), dim3(1024), 0, stream,
                       kpts, pix_ws, vidx_ws, row_start_ws);
    hipLaunchKernelGGL(k3_gather, dim3(1024), dim3(1024), 0, stream,
                       seg, conv_w, conv_b, pix_ws, vidx_ws, row_start_ws,
                       pool_ws, cent_ws, avg_ws, max_ws);
    hipLaunchKernelGGL(k2_mlp, dim3(4), dim3(256), 0, stream,
                       avg_ws, max_ws, w1, w2, s_ws);
    hipLaunchKernelGGL(k4_final, dim3(Mm / 16, 4), dim3(256), 0, stream,
                       pool_ws, cent_ws, lin_w, lin_b, s_ws, out);
}